// Round 3
// baseline (1090.092 us; speedup 1.0000x reference)
//
#include <hip/hip_runtime.h>
#include <math.h>

#define NN 50000
#define EE 1600000
#define FIN 32
#define HID_ 128
#define ED_ 16
#define GG 512
#define MH_ 512
#define MO_ 512

typedef float v2f __attribute__((ext_vector_type(2)));

#if __has_builtin(__builtin_amdgcn_exp2f)
#define EXP2(x) __builtin_amdgcn_exp2f(x)
#else
#define EXP2(x) exp2f(x)
#endif

__device__ __forceinline__ v2f exp2v(v2f a) {
  v2f r; r.x = EXP2(a.x); r.y = EXP2(a.y); return r;
}

// butterfly sum over 16-lane groups via immediate ds_swizzle (XOR bit-mode)
__device__ __forceinline__ float bfly16(float p) {
  p += __uint_as_float(__builtin_amdgcn_ds_swizzle(__float_as_uint(p), 0x041F));
  p += __uint_as_float(__builtin_amdgcn_ds_swizzle(__float_as_uint(p), 0x081F));
  p += __uint_as_float(__builtin_amdgcn_ds_swizzle(__float_as_uint(p), 0x101F));
  p += __uint_as_float(__builtin_amdgcn_ds_swizzle(__float_as_uint(p), 0x201F));
  return p;
}

// ---------------- CSR build ----------------

__global__ void hist_kernel(const int* __restrict__ dst, int* __restrict__ cnt) {
  int e = blockIdx.x * 256 + threadIdx.x;
  if (e < EE) atomicAdd(&cnt[dst[e]], 1);
}

__global__ __launch_bounds__(256) void scan1_kernel(const int* __restrict__ in, int n,
                                                    int* __restrict__ out,
                                                    int* __restrict__ bsums) {
  int chunk = blockIdx.x;
  int base = chunk * 1024;
  int t = threadIdx.x;
  int idx = base + t * 4;
  int v0 = (idx + 0 < n) ? in[idx + 0] : 0;
  int v1 = (idx + 1 < n) ? in[idx + 1] : 0;
  int v2 = (idx + 2 < n) ? in[idx + 2] : 0;
  int v3 = (idx + 3 < n) ? in[idx + 3] : 0;
  int ts = v0 + v1 + v2 + v3;
  int lane = t & 63, w = t >> 6;
  int s = ts;
#pragma unroll
  for (int off = 1; off < 64; off <<= 1) {
    int o = __shfl_up(s, off);
    if (lane >= off) s += o;
  }
  __shared__ int wsum[4];
  if (lane == 63) wsum[w] = s;
  __syncthreads();
  int woff = 0;
  for (int i = 0; i < w; i++) woff += wsum[i];
  int excl = woff + s - ts;
  int run = excl;
  run += v0; if (idx + 0 < n) out[idx + 0] = run;
  run += v1; if (idx + 1 < n) out[idx + 1] = run;
  run += v2; if (idx + 2 < n) out[idx + 2] = run;
  run += v3; if (idx + 3 < n) out[idx + 3] = run;
  if (t == 255) bsums[chunk] = woff + s;
}

__global__ void scan_add_kernel(int* __restrict__ rowptr, const int* __restrict__ bscan, int n) {
  int i = blockIdx.x * 256 + threadIdx.x;
  if (i == 0) rowptr[0] = 0;
  if (i < n) {
    int chunk = i >> 10;
    if (chunk > 0) rowptr[1 + i] += bscan[chunk - 1];
  }
}

__global__ void scatter_kernel(const int* __restrict__ src, const int* __restrict__ dst,
                               const int* __restrict__ rowptr, int* __restrict__ fill,
                               int2* __restrict__ csr) {
  int e = blockIdx.x * 256 + threadIdx.x;
  if (e >= EE) return;
  int v = dst[e];
  int pos = rowptr[v] + atomicAdd(&fill[v], 1);
  csr[pos] = make_int2(src[e], e);
}

// ea_csr[j][:] = ea[csr[j].y][:]   (4 lanes per row, 16B each)
__global__ void permute_ea(const int2* __restrict__ csr, const float* __restrict__ ea,
                           float* __restrict__ ea_csr) {
  int t = blockIdx.x * 256 + threadIdx.x;
  int j = t >> 2, q = t & 3;
  if (j >= EE) return;
  int eid = csr[j].y;
  ((float4*)ea_csr)[t] = ((const float4*)ea)[eid * 4 + q];
}

// loop_attr[v] = mean of incoming edge_attr (0 if no incoming edges)
__global__ __launch_bounds__(256) void loopattr_kernel(const int* __restrict__ rowptr,
                                                       const int2* __restrict__ csr,
                                                       const float* __restrict__ ea,
                                                       float* __restrict__ la) {
  int wid = threadIdx.x >> 6, lane = threadIdx.x & 63;
  int v = __builtin_amdgcn_readfirstlane(blockIdx.x * 4 + wid);
  if (v >= NN) return;
  int s = __builtin_amdgcn_readfirstlane(rowptr[v]);
  int e = __builtin_amdgcn_readfirstlane(rowptr[v + 1]);
  int k = lane >> 4;
  int d = lane & 15;
  float acc = 0.f;
  for (int j = s + k; j < e; j += 4) acc += ea[(size_t)csr[j].y * 16 + d];
  acc += __shfl_xor(acc, 16);
  acc += __shfl_xor(acc, 32);
  if (lane < 16) la[(size_t)v * 16 + d] = (e > s) ? acc / (float)(e - s) : 0.f;
}

// ---------------- node linear transforms ----------------

template <int F>
__global__ __launch_bounds__(256) void node_transform(const float* __restrict__ h,
                                                      const float* __restrict__ Wlm,
                                                      const float* __restrict__ blm,
                                                      const float* __restrict__ Wrm,
                                                      const float* __restrict__ brm,
                                                      float* __restrict__ xl,
                                                      float* __restrict__ xr, int nnodes) {
  __shared__ float hs[F * 32];  // [k][i]
  int v0 = blockIdx.x * 32;
  int t = threadIdx.x;
  for (int idx = t; idx < 32 * F; idx += 256) {
    int i = idx / F, k = idx - i * F;
    float val = (v0 + i < nnodes) ? h[(size_t)(v0 + i) * F + k] : 0.f;
    hs[k * 32 + i] = val;
  }
  __syncthreads();
  int cc = t & 127;
  bool isL = t < 128;
  const float* W = isL ? Wlm : Wrm;
  float4 acc[8];
#pragma unroll
  for (int q = 0; q < 8; q++) acc[q] = make_float4(0.f, 0.f, 0.f, 0.f);
  const float4* hs4 = (const float4*)hs;
  for (int k = 0; k < F; k++) {
    float w = W[k * 128 + cc];
#pragma unroll
    for (int q = 0; q < 8; q++) {
      float4 hv = hs4[k * 8 + q];
      acc[q].x = fmaf(hv.x, w, acc[q].x);
      acc[q].y = fmaf(hv.y, w, acc[q].y);
      acc[q].z = fmaf(hv.z, w, acc[q].z);
      acc[q].w = fmaf(hv.w, w, acc[q].w);
    }
  }
  float b = isL ? blm[cc] : brm[cc];
  float* dstp = isL ? xl : xr;
  int nb = nnodes - v0; if (nb > 32) nb = 32;
#pragma unroll
  for (int q = 0; q < 8; q++) {
    if (4 * q + 0 < nb) dstp[(size_t)(v0 + 4 * q + 0) * 128 + cc] = acc[q].x + b;
    if (4 * q + 1 < nb) dstp[(size_t)(v0 + 4 * q + 1) * 128 + cc] = acc[q].y + b;
    if (4 * q + 2 < nb) dstp[(size_t)(v0 + 4 * q + 2) * 128 + cc] = acc[q].z + b;
    if (4 * q + 3 < nb) dstp[(size_t)(v0 + 4 * q + 3) * 128 + cc] = acc[q].w + b;
  }
}

// ---------------- GATv2 edge scoring + online-softmax aggregation ----------------
// One wave per node. Lane owns channel pair (lane, 64+lane) as <2 x float> so the
// backend can use v_pk_* ops. PERM: ea rows pre-permuted into CSR order.

template <bool PERM>
__global__ __launch_bounds__(256) void gat_aggregate(
    const float* __restrict__ xl, const float* __restrict__ xr,
    const int* __restrict__ rowptr, const int2* __restrict__ csr,
    const float* __restrict__ eaJ, const float* __restrict__ la,
    const float* __restrict__ We, const float* __restrict__ att,
    const float* __restrict__ bias, float* __restrict__ hout, int relu) {
  int wid = threadIdx.x >> 6, lane = threadIdx.x & 63;
  int v = __builtin_amdgcn_readfirstlane(blockIdx.x * 4 + wid);
  if (v >= NN) return;
  v2f wec[16];
#pragma unroll
  for (int k = 0; k < 16; k++) {
    wec[k].x = We[k * 128 + lane];
    wec[k].y = We[k * 128 + 64 + lane];
  }
  const float L2E = 1.44269504088896340736f;
  v2f av; av.x = att[lane] * L2E; av.y = att[64 + lane] * L2E;
  v2f xrv; xrv.x = xr[(size_t)v * 128 + lane]; xrv.y = xr[(size_t)v * 128 + 64 + lane];

  auto score = [&](int u, const float* eaP, v2f& xu, v2f& p) {
    float ec[16];
#pragma unroll
    for (int k = 0; k < 4; k++) {
      float4 q = ((const float4*)eaP)[k];
      ec[4 * k + 0] = q.x; ec[4 * k + 1] = q.y;
      ec[4 * k + 2] = q.z; ec[4 * k + 3] = q.w;
    }
    const float* xlu = xl + (size_t)u * 128;
    xu.x = xlu[lane]; xu.y = xlu[64 + lane];
    v2f m = xrv + xu;
#pragma unroll
    for (int k = 0; k < 16; k++) {
      v2f e2; e2.x = ec[k]; e2.y = ec[k];
      m = __builtin_elementwise_fma(e2, wec[k], m);
    }
    m = __builtin_elementwise_max(m, 0.2f * m);  // LeakyReLU
    v2f q = av * m;
    p.x = bfly16(q.x);
    p.y = bfly16(q.y);
  };

  // self-loop initializes the online softmax (exp2 domain)
  v2f mx, den, acc;
  {
    v2f xs, ps;
    score(v, la + (size_t)v * 16, xs, ps);
    mx = ps; den.x = 1.f; den.y = 1.f; acc = xs;
  }
  int start = __builtin_amdgcn_readfirstlane(rowptr[v]);
  int end = __builtin_amdgcn_readfirstlane(rowptr[v + 1]);
  int j = start;
  for (; j + 4 <= end; j += 4) {
    int2 e0 = csr[j], e1 = csr[j + 1], e2 = csr[j + 2], e3 = csr[j + 3];
    int u0 = __builtin_amdgcn_readfirstlane(e0.x);
    int u1 = __builtin_amdgcn_readfirstlane(e1.x);
    int u2 = __builtin_amdgcn_readfirstlane(e2.x);
    int u3 = __builtin_amdgcn_readfirstlane(e3.x);
    v2f xa, pa, xb, pb, xc, pc, xd, pd;
    if (PERM) {
      const float* b = eaJ + (size_t)j * 16;
      score(u0, b, xa, pa);
      score(u1, b + 16, xb, pb);
      score(u2, b + 32, xc, pc);
      score(u3, b + 48, xd, pd);
    } else {
      score(u0, eaJ + (size_t)e0.y * 16, xa, pa);
      score(u1, eaJ + (size_t)e1.y * 16, xb, pb);
      score(u2, eaJ + (size_t)e2.y * 16, xc, pc);
      score(u3, eaJ + (size_t)e3.y * 16, xd, pd);
    }
    v2f pm = __builtin_elementwise_max(__builtin_elementwise_max(pa, pb),
                                       __builtin_elementwise_max(pc, pd));
    bool up = (pm.x > mx.x) || (pm.y > mx.y);
    if (__any(up)) {
      v2f nm = __builtin_elementwise_max(mx, pm);
      v2f f = exp2v(mx - nm);
      v2f wa = exp2v(pa - nm), wb = exp2v(pb - nm);
      v2f wc = exp2v(pc - nm), wd = exp2v(pd - nm);
      den = __builtin_elementwise_fma(f, den, (wa + wb) + (wc + wd));
      v2f wx = __builtin_elementwise_fma(wa, xa,
               __builtin_elementwise_fma(wb, xb,
               __builtin_elementwise_fma(wc, xc, wd * xd)));
      acc = __builtin_elementwise_fma(f, acc, wx);
      mx = nm;
    } else {  // exact skip: f == 1
      v2f wa = exp2v(pa - mx), wb = exp2v(pb - mx);
      v2f wc = exp2v(pc - mx), wd = exp2v(pd - mx);
      den += (wa + wb) + (wc + wd);
      acc = __builtin_elementwise_fma(wa, xa,
            __builtin_elementwise_fma(wb, xb,
            __builtin_elementwise_fma(wc, xc,
            __builtin_elementwise_fma(wd, xd, acc))));
    }
  }
  for (; j < end; ++j) {
    int2 e0 = csr[j];
    int u0 = __builtin_amdgcn_readfirstlane(e0.x);
    v2f xa, pa;
    score(u0, PERM ? eaJ + (size_t)j * 16 : eaJ + (size_t)e0.y * 16, xa, pa);
    bool up = (pa.x > mx.x) || (pa.y > mx.y);
    if (__any(up)) {
      v2f nm = __builtin_elementwise_max(mx, pa);
      v2f f = exp2v(mx - nm);
      v2f wa = exp2v(pa - nm);
      den = __builtin_elementwise_fma(f, den, wa);
      acc = __builtin_elementwise_fma(f, acc, wa * xa);
      mx = nm;
    } else {
      v2f wa = exp2v(pa - mx);
      den += wa;
      acc = __builtin_elementwise_fma(wa, xa, acc);
    }
  }
  v2f o = acc / den;
  o.x += bias[lane]; o.y += bias[64 + lane];
  if (relu) { o.x = fmaxf(o.x, 0.f); o.y = fmaxf(o.y, 0.f); }
  hout[(size_t)v * 128 + lane] = o.x;
  hout[(size_t)v * 128 + 64 + lane] = o.y;
}

// ---------------- pooling + MLP ----------------

__global__ void gptr_kernel(const int* __restrict__ batch, int* __restrict__ gptr) {
  int g = blockIdx.x * 256 + threadIdx.x;
  if (g > GG) return;
  int lo = 0, hi = NN;
  while (lo < hi) {
    int mid = (lo + hi) >> 1;
    if (batch[mid] < g) lo = mid + 1; else hi = mid;
  }
  gptr[g] = lo;
}

__global__ void pool_kernel(const float* __restrict__ h, const int* __restrict__ gptr,
                            float* __restrict__ gp) {
  int gi = blockIdx.x;
  int c = threadIdx.x;  // 128
  int s = gptr[gi], e = gptr[gi + 1];
  float acc = 0.f;
  for (int v = s; v < e; v++) acc += h[(size_t)v * 128 + c];
  gp[gi * 128 + c] = acc;
}

__global__ __launch_bounds__(256) void mlp1_kernel(const float* __restrict__ gp,
                                                   const float* __restrict__ mW1,
                                                   const float* __restrict__ mb1,
                                                   const float* __restrict__ lng,
                                                   const float* __restrict__ lnb,
                                                   float* __restrict__ z) {
  int row = blockIdx.x;
  int t = threadIdx.x;
  __shared__ float gs[128];
  if (t < 128) gs[t] = gp[row * 128 + t];
  __syncthreads();
  int c0 = t, c1 = t + 256;
  float z0 = 0.f, z1 = 0.f;
  for (int k = 0; k < 128; k++) {
    float gk = gs[k];
    z0 = fmaf(gk, mW1[k * 512 + c0], z0);
    z1 = fmaf(gk, mW1[k * 512 + c1], z1);
  }
  z0 += mb1[c0]; z1 += mb1[c1];
  z0 = fmaxf(z0, 0.f); z1 = fmaxf(z1, 0.f);
  float s = z0 + z1, q = z0 * z0 + z1 * z1;
#pragma unroll
  for (int off = 32; off > 0; off >>= 1) {
    s += __shfl_xor(s, off);
    q += __shfl_xor(q, off);
  }
  __shared__ float red[8];
  int lane = t & 63, w = t >> 6;
  if (lane == 0) { red[w] = s; red[4 + w] = q; }
  __syncthreads();
  float S = red[0] + red[1] + red[2] + red[3];
  float Q = red[4] + red[5] + red[6] + red[7];
  float mu = S / 512.f;
  float var = Q / 512.f - mu * mu;
  float inv = 1.f / sqrtf(var + 1e-5f);
  z[row * 512 + c0] = (z0 - mu) * inv * lng[c0] + lnb[c0];
  z[row * 512 + c1] = (z1 - mu) * inv * lng[c1] + lnb[c1];
}

__global__ __launch_bounds__(256) void mlp2_kernel(const float* __restrict__ z,
                                                   const float* __restrict__ mW2,
                                                   const float* __restrict__ mb2,
                                                   float* __restrict__ out) {
  int row = blockIdx.x;
  int t = threadIdx.x;
  __shared__ float zs[512];
  for (int i = t; i < 512; i += 256) zs[i] = z[row * 512 + i];
  __syncthreads();
  int c0 = t, c1 = t + 256;
  float o0 = 0.f, o1 = 0.f;
  for (int k = 0; k < 512; k++) {
    float zk = zs[k];
    o0 = fmaf(zk, mW2[k * 512 + c0], o0);
    o1 = fmaf(zk, mW2[k * 512 + c1], o1);
  }
  out[row * 512 + c0] = o0 + mb2[c0];
  out[row * 512 + c1] = o1 + mb2[c1];
}

// ---------------- launcher ----------------

extern "C" void kernel_launch(void* const* d_in, const int* in_sizes, int n_in,
                              void* d_out, int out_size, void* d_ws, size_t ws_size,
                              hipStream_t stream) {
  const float* x = (const float*)d_in[0];
  const int* ei = (const int*)d_in[1];
  const int* srcE = ei;
  const int* dstE = ei + EE;
  const float* ea = (const float*)d_in[2];
  const int* batch = (const int*)d_in[3];
  const float* Wl[3] = {(const float*)d_in[4], (const float*)d_in[11], (const float*)d_in[18]};
  const float* bl[3] = {(const float*)d_in[5], (const float*)d_in[12], (const float*)d_in[19]};
  const float* Wr[3] = {(const float*)d_in[6], (const float*)d_in[13], (const float*)d_in[20]};
  const float* br[3] = {(const float*)d_in[7], (const float*)d_in[14], (const float*)d_in[21]};
  const float* Wek[3] = {(const float*)d_in[8], (const float*)d_in[15], (const float*)d_in[22]};
  const float* attk[3] = {(const float*)d_in[9], (const float*)d_in[16], (const float*)d_in[23]};
  const float* bk[3] = {(const float*)d_in[10], (const float*)d_in[17], (const float*)d_in[24]};
  const float* mW1 = (const float*)d_in[25];
  const float* mb1 = (const float*)d_in[26];
  const float* lng = (const float*)d_in[27];
  const float* lnb = (const float*)d_in[28];
  const float* mW2 = (const float*)d_in[29];
  const float* mb2 = (const float*)d_in[30];
  float* outp = (float*)d_out;

  char* W = (char*)d_ws;
  size_t off = 0;
  auto take = [&](size_t b) -> void* {
    void* p = W + off;
    off += (b + 255) & ~(size_t)255;
    return p;
  };
  int* cnt = (int*)take(NN * 4);
  int* rowptr = (int*)take((NN + 1) * 4);
  int* bsums = (int*)take(64 * 4);
  int* bscan = (int*)take(64 * 4);
  int* dummy = (int*)take(64 * 4);
  int2* csr = (int2*)take((size_t)EE * 8);
  float* la = (float*)take((size_t)NN * 16 * 4);
  float* xl = (float*)take((size_t)NN * HID_ * 4);
  float* xr = (float*)take((size_t)NN * HID_ * 4);
  float* hbuf = (float*)take((size_t)NN * HID_ * 4);
  int* gptr = (int*)take((GG + 1) * 4);
  float* gpool = (float*)take((size_t)GG * HID_ * 4);
  float* z = (float*)take((size_t)GG * MH_ * 4);
  float* ea_csr = (float*)take((size_t)EE * 16 * 4);  // optional, last
  bool perm = (off <= ws_size);
  (void)n_in; (void)in_sizes; (void)out_size;

  // CSR build
  hipMemsetAsync(cnt, 0, NN * 4, stream);
  hist_kernel<<<(EE + 255) / 256, 256, 0, stream>>>(dstE, cnt);
  scan1_kernel<<<49, 256, 0, stream>>>(cnt, NN, rowptr + 1, bsums);
  scan1_kernel<<<1, 256, 0, stream>>>(bsums, 49, bscan, dummy);
  scan_add_kernel<<<(NN + 255) / 256, 256, 0, stream>>>(rowptr, bscan, NN);
  hipMemsetAsync(cnt, 0, NN * 4, stream);
  scatter_kernel<<<(EE + 255) / 256, 256, 0, stream>>>(srcE, dstE, rowptr, cnt, csr);
  if (perm)
    permute_ea<<<(EE * 4 + 255) / 256, 256, 0, stream>>>(csr, ea, ea_csr);
  loopattr_kernel<<<(NN + 3) / 4, 256, 0, stream>>>(rowptr, csr, ea, la);

  // 3 GATv2 layers
  for (int l = 0; l < 3; l++) {
    if (l == 0)
      node_transform<FIN><<<(NN + 31) / 32, 256, 0, stream>>>(x, Wl[0], bl[0], Wr[0], br[0],
                                                              xl, xr, NN);
    else
      node_transform<HID_><<<(NN + 31) / 32, 256, 0, stream>>>(hbuf, Wl[l], bl[l], Wr[l], br[l],
                                                               xl, xr, NN);
    if (perm)
      gat_aggregate<true><<<(NN + 3) / 4, 256, 0, stream>>>(xl, xr, rowptr, csr, ea_csr, la,
                                                            Wek[l], attk[l], bk[l], hbuf,
                                                            (l < 2) ? 1 : 0);
    else
      gat_aggregate<false><<<(NN + 3) / 4, 256, 0, stream>>>(xl, xr, rowptr, csr, ea, la,
                                                             Wek[l], attk[l], bk[l], hbuf,
                                                             (l < 2) ? 1 : 0);
  }

  // pooling + MLP head
  gptr_kernel<<<3, 256, 0, stream>>>(batch, gptr);
  pool_kernel<<<GG, 128, 0, stream>>>(hbuf, gptr, gpool);
  mlp1_kernel<<<GG, 256, 0, stream>>>(gpool, mW1, mb1, lng, lnb, z);
  mlp2_kernel<<<GG, 256, 0, stream>>>(z, mW2, mb2, outp);
}